// Round 10
// baseline (128.448 us; speedup 1.0000x reference)
//
#include <hip/hip_runtime.h>
#include <stdint.h>

#define NB 4096          // number of boxes
#define NBLK 64          // 64 blocks of 64 boxes
#define IOU_THR 0.5f
#define ECAP 1024        // entry capacity per source block bucket
#define RANKB 256        // rank blocks (16 boxes each)
#define NTRI (NBLK * (NBLK + 1) / 2)   // 2080 upper-triangle tiles

typedef unsigned long long u64;

__device__ __forceinline__ u64 readlane64(u64 v, int lane) {
    unsigned lo = (unsigned)__builtin_amdgcn_readlane((int)(unsigned)(v & 0xffffffffull), lane);
    unsigned hi = (unsigned)__builtin_amdgcn_readlane((int)(unsigned)(v >> 32), lane);
    return ((u64)hi << 32) | (u64)lo;
}

// ---- fused front: pred (0-63), rank+sorted-scatter (64-319), zero (320) ----
// Rank waves write the SORTED offset-boxes directly (ranks are a permutation),
// so edge_kernel needs no gathers. Each rank block computes maxc locally
// (boxes is 64 KB, L2-resident).
__global__ void __launch_bounds__(256) fused_front(
        const float* __restrict__ boxes, const float* __restrict__ scores,
        const int* __restrict__ cls,
        const float* __restrict__ loc, const float* __restrict__ deltas,
        const int* __restrict__ stride_p,
        float* __restrict__ pred_out, int* __restrict__ sidx,
        float* __restrict__ sboxes, float* __restrict__ sareas,
        int* __restrict__ counts /* [64 buckets][64 donec][1 master] */) {
    __shared__ __align__(16) float sh[NB];
    __shared__ float red[4];
    int blk = blockIdx.x;
    int t = threadIdx.x;

    if (blk < 64) {
        // ---- pred boxes + centerness ----
        int i = blk * 256 + t;
        float s = (float)stride_p[0];
        float2 p = ((const float2*)loc)[i];
        float4 d = ((const float4*)deltas)[i];
        float c0 = fmaxf(d.x, 0.f), c1 = fmaxf(d.y, 0.f);
        float c2 = fmaxf(d.z, 0.f), c3 = fmaxf(d.w, 0.f);
        float b0 = p.x - c0 * s;
        float b1 = p.y - c1 * s;
        float b2 = p.x + c2 * s;
        float b3 = p.y + c3 * s;
        float lr_min = fminf(d.x, d.z), tb_min = fminf(d.y, d.w);
        float lr_max = fmaxf(d.x, d.z), tb_max = fmaxf(d.y, d.w);
        float cent = sqrtf((lr_min * tb_min) / (lr_max * tb_max));
        if (d.x == -1.f && d.y == -1.f && d.z == -1.f && d.w == -1.f) cent = -1.f;
        float* o = pred_out + (size_t)i * 5;
        o[0] = b0; o[1] = b1; o[2] = b2; o[3] = b3; o[4] = cent;
    } else if (blk < 64 + RANKB) {
        // ---- rank (wave-per-box, 4 boxes/wave) + sorted scatter ----
        for (int i = t; i < NB; i += 256) sh[i] = scores[i];
        // local max over all box coords (L2-resident re-read)
        float m = -3.0e38f;
        for (int i = t; i < NB * 4; i += 256) m = fmaxf(m, boxes[i]);
        for (int o = 32; o > 0; o >>= 1) m = fmaxf(m, __shfl_down(m, o));
        if ((t & 63) == 0) red[t >> 6] = m;
        __syncthreads();                       // covers sh[] and red[]
        float mc1 = fmaxf(fmaxf(red[0], red[1]), fmaxf(red[2], red[3])) + 1.0f;

        int wave = t >> 6, lane = t & 63;
        int base = (blk - 64) * 16 + wave * 4;     // 4 consecutive boxes
        float my0 = sh[base + 0], my1 = sh[base + 1];
        float my2 = sh[base + 2], my3 = sh[base + 3];
        int c0 = 0, c1 = 0, c2 = 0, c3 = 0;
#pragma unroll 8
        for (int k = 0; k < 64; ++k) {
            int j = lane + k * 64;                 // 2-way LDS bank alias: free
            float sj = sh[j];
            c0 += (sj > my0) || (sj == my0 && j < base + 0);
            c1 += (sj > my1) || (sj == my1 && j < base + 1);
            c2 += (sj > my2) || (sj == my2 && j < base + 2);
            c3 += (sj > my3) || (sj == my3 && j < base + 3);
        }
        for (int o = 32; o > 0; o >>= 1) {
            c0 += __shfl_down(c0, o); c1 += __shfl_down(c1, o);
            c2 += __shfl_down(c2, o); c3 += __shfl_down(c3, o);
        }
        if (lane == 0) {
            int rk[4] = { c0, c1, c2, c3 };
#pragma unroll
            for (int k = 0; k < 4; ++k) {
                int i = base + k, rank = rk[k];
                sidx[rank] = i;
                float off = (float)cls[i] * mc1;
                float4 b = ((const float4*)boxes)[i];
                b.x += off; b.y += off; b.z += off; b.w += off;
                ((float4*)sboxes)[rank] = b;
                sareas[rank] = (b.z - b.x) * (b.w - b.y);
            }
        }
    } else {
        // ---- zero bucket counts + donec + master (129 ints) ----
        if (t < 2 * NBLK + 1) counts[t] = 0;
    }
}

// -------- edge extraction (coalesced tiles) + tree-signal + last-block scan --
// Entry (16 B): qword0 = local_row | (word_col<<8), qword1 = suppression word.
// Entries written with device-scope 64-bit atomics (coherent point — no
// per-block release fence needed). Done-signal is a 2-level tree: per-bucket
// donec[r] (<=64 adds each), bucket-completer bumps master (64 adds total) —
// avoids 2080 serialized same-address atomics (round-9 lesson).
__global__ void __launch_bounds__(64) edge_kernel(
        const float* __restrict__ sboxes, const float* __restrict__ sareas,
        const int* __restrict__ sidx,
        int* __restrict__ counts /* [64 buckets][64 donec][1 master] */,
        uint4* __restrict__ entries, float* __restrict__ keep_out) {
    // decode upper-triangle tile (r <= c) from linear block id (uniform scalar)
    int idx = blockIdx.x, r = 0;
    while (idx >= NBLK - r) { idx -= NBLK - r; ++r; }
    int c = r + idx;

    __shared__ float4 cb[64];
    __shared__ float ca[64];
    __shared__ int islast;
    int t = threadIdx.x;                // 64 threads = one wave

    float4 rb = ((const float4*)sboxes)[r * 64 + t];
    float ra = sareas[r * 64 + t];
    if (c == r) {
        cb[t] = rb; ca[t] = ra;
    } else {
        cb[t] = ((const float4*)sboxes)[c * 64 + t];
        ca[t] = sareas[c * 64 + t];
    }
    __syncthreads();

    u64 w = 0;
#pragma unroll 8
    for (int j = 0; j < 64; ++j) {
        float4 b = cb[j];
        float xi = fminf(rb.z, b.z) - fmaxf(rb.x, b.x);
        float yi = fminf(rb.w, b.w) - fmaxf(rb.y, b.y);
        float inter = fmaxf(xi, 0.f) * fmaxf(yi, 0.f);
        float iou = inter / (ra + ca[j] - inter);
        w |= (u64)(iou > IOU_THR) << j;
    }
    if (c == r) w &= ~(1ull << t);      // drop self-overlap bit
    if (w) {
        int slot = atomicAdd(&counts[r], 1);
        if (slot < ECAP) {
            u64* e = (u64*)&entries[r * ECAP + slot];
            atomicExch(e,     (u64)(unsigned)(t | (c << 8)));  // meta qword
            atomicExch(e + 1, w);                              // word qword
        }
    }

    // ---- 2-level done signaling (deadlock-free: all work first) ----
    asm volatile("s_waitcnt vmcnt(0)" ::: "memory");  // own atomics complete
    if (t == 0) {
        islast = 0;
        int old = atomicAdd(&counts[NBLK + r], 1);        // bucket r done count
        if (old == (NBLK - r) - 1) {                      // bucket complete
            int o2 = atomicAdd(&counts[2 * NBLK], 1);     // master
            islast = (o2 == NBLK - 1);
        }
    }
    __syncthreads();
    if (!islast) return;
    __threadfence();                    // acquire: invalidate stale L1/L2 once

    // ================= serial greedy scan (this one wave) =================
    const int lane = t;
    int cnt_l = counts[lane];           // lane b holds bucket b's entry count
    u64 accv = 0;                       // lane w = removed-word w
    u64 keptall = 0;                    // lane b = keptm of block b
    u64 self = 1ull << lane;

    uint4 cur = entries[lane];          // depth-2 prefetch
    uint4 n1  = entries[ECAP + lane];
    for (int b = 0; b < NBLK; ++b) {
        uint4 n2;
        if (b < NBLK - 2) n2 = entries[(u64)(b + 2) * ECAP + lane];

        int cnt = __builtin_amdgcn_readlane(cnt_l, b);
        if (cnt > ECAP) cnt = ECAP;
        int cfast = cnt < 64 ? cnt : 64;

        // pass 1: build within-block column words from diagonal entries
        u64 colw = self;
        for (int e = 0; e < cfast; ++e) {
            unsigned meta = (unsigned)__builtin_amdgcn_readlane((int)cur.x, e);
            int l = meta & 255, cw = meta >> 8;
            if (cw == b) {
                unsigned lo = (unsigned)__builtin_amdgcn_readlane((int)cur.z, e);
                unsigned hi = (unsigned)__builtin_amdgcn_readlane((int)cur.w, e);
                if (lane == l) colw |= ((u64)hi << 32) | lo;
            }
        }
        for (int e = 64; e < cnt; ++e) {        // overflow path (rare)
            uint4 x = entries[(u64)b * ECAP + e];
            int l = x.x & 255, cw = x.x >> 8;
            if (cw == b && lane == l) colw |= ((u64)x.w << 32) | x.z;
        }

        // decision: optimistic ballot; serial greedy only over conflicts
        u64 rem = readlane64(accv, b);
        u64 avail = ~rem;
        u64 edges = colw & avail & ~self;
        u64 involved = __ballot(edges != 0ull) & avail;
        u64 keptm = avail & ~involved;
        u64 sub = involved;
        while (sub) {
            int i = (int)__builtin_ctzll(sub);  // highest score first
            keptm |= 1ull << i;
            u64 ci = readlane64(colw, i);
            sub &= ~(ci | (1ull << i));
        }
        if (lane == b) keptall = keptm;

        // pass 2: merge kept rows' words into the removed accumulator
        for (int e = 0; e < cfast; ++e) {
            unsigned meta = (unsigned)__builtin_amdgcn_readlane((int)cur.x, e);
            unsigned lo   = (unsigned)__builtin_amdgcn_readlane((int)cur.z, e);
            unsigned hi   = (unsigned)__builtin_amdgcn_readlane((int)cur.w, e);
            int l = meta & 255, cw = meta >> 8;
            if (((keptm >> l) & 1ull) && lane == cw) accv |= ((u64)hi << 32) | lo;
        }
        for (int e = 64; e < cnt; ++e) {        // overflow path (rare)
            uint4 x = entries[(u64)b * ECAP + e];
            int l = x.x & 255, cw = x.x >> 8;
            if (((keptm >> l) & 1ull) && lane == cw) accv |= ((u64)x.w << 32) | x.z;
        }
        cur = n1; n1 = n2;
    }

    // epilogue: write keep mask via sorted-index scatter
#pragma unroll 8
    for (int bb = 0; bb < NBLK; ++bb) {
        u64 kw = readlane64(keptall, bb);
        int oidx = sidx[bb * 64 + lane];
        keep_out[oidx] = ((kw >> lane) & 1ull) ? 1.0f : 0.0f;
    }
}

extern "C" void kernel_launch(void* const* d_in, const int* in_sizes, int n_in,
                              void* d_out, int out_size, void* d_ws, size_t ws_size,
                              hipStream_t stream) {
    const float* boxes   = (const float*)d_in[0];   // (4096,4)
    const float* scores  = (const float*)d_in[1];   // (4096,)
    const int*   cls     = (const int*)d_in[2];     // (4096,)
    const float* loc     = (const float*)d_in[3];   // (16384,2)
    const float* deltas  = (const float*)d_in[4];   // (16384,4)
    const int*   stride  = (const int*)d_in[5];     // scalar

    float* out = (float*)d_out;
    float* keep_out = out;          // 4096 floats (bool as 0/1)
    float* pred_out = out + NB;     // 16384*5 floats

    // workspace layout (16B-aligned pieces), ~1.1 MiB total
    char* ws = (char*)d_ws;
    int*   sidx    = (int*)ws;                       ws += NB * sizeof(int);
    float* sboxes  = (float*)ws;                     ws += NB * 4 * sizeof(float);
    float* sareas  = (float*)ws;                     ws += NB * sizeof(float);
    int*   counts  = (int*)ws;                       ws += (2 * NBLK + 1) * sizeof(int) + 12;
    uint4* entries = (uint4*)ws;                     // NBLK * ECAP * 16 B = 1 MiB

    fused_front<<<64 + RANKB + 1, 256, 0, stream>>>(boxes, scores, cls, loc, deltas,
                                                    stride, pred_out, sidx, sboxes,
                                                    sareas, counts);
    edge_kernel<<<NTRI, 64, 0, stream>>>(sboxes, sareas, sidx, counts, entries,
                                         keep_out);
}

// Round 11
// 119.221 us; speedup vs baseline: 1.0774x; 1.0774x over previous
//
#include <hip/hip_runtime.h>
#include <stdint.h>

#define NB 4096          // number of boxes
#define NBLK 64          // 64 blocks of 64 boxes
#define IOU_THR 0.5f
#define ECAP 1024        // entry capacity per source block bucket
#define RANKB 256        // rank blocks (16 boxes each)
#define NTRI (NBLK * (NBLK + 1) / 2)   // 2080 upper-triangle tiles

typedef unsigned long long u64;

__device__ __forceinline__ u64 readlane64(u64 v, int lane) {
    unsigned lo = (unsigned)__builtin_amdgcn_readlane((int)(unsigned)(v & 0xffffffffull), lane);
    unsigned hi = (unsigned)__builtin_amdgcn_readlane((int)(unsigned)(v >> 32), lane);
    return ((u64)hi << 32) | (u64)lo;
}

// ---- fused front: pred (0-63), rank+raw-sorted-scatter (64-319), maxc (320) --
// Rank waves scatter sorted RAW boxes + cls (ranks are a permutation); class
// offsets are applied inside edge_kernel (bit-exact same float ops), so rank
// blocks need neither maxc nor the 64 KB boxes read (round-10 lesson).
__global__ void __launch_bounds__(256) fused_front(
        const float* __restrict__ boxes, const float* __restrict__ scores,
        const int* __restrict__ cls,
        const float* __restrict__ loc, const float* __restrict__ deltas,
        const int* __restrict__ stride_p,
        float* __restrict__ pred_out, int* __restrict__ sidx,
        float* __restrict__ sboxes, int* __restrict__ scls,
        float* __restrict__ maxc,
        int* __restrict__ counts /* [64 buckets][64 donec][1 master] */) {
    __shared__ __align__(16) float sh[NB];
    __shared__ float red[4];
    int blk = blockIdx.x;
    int t = threadIdx.x;

    if (blk < 64) {
        // ---- pred boxes + centerness ----
        int i = blk * 256 + t;
        float s = (float)stride_p[0];
        float2 p = ((const float2*)loc)[i];
        float4 d = ((const float4*)deltas)[i];
        float c0 = fmaxf(d.x, 0.f), c1 = fmaxf(d.y, 0.f);
        float c2 = fmaxf(d.z, 0.f), c3 = fmaxf(d.w, 0.f);
        float b0 = p.x - c0 * s;
        float b1 = p.y - c1 * s;
        float b2 = p.x + c2 * s;
        float b3 = p.y + c3 * s;
        float lr_min = fminf(d.x, d.z), tb_min = fminf(d.y, d.w);
        float lr_max = fmaxf(d.x, d.z), tb_max = fmaxf(d.y, d.w);
        float cent = sqrtf((lr_min * tb_min) / (lr_max * tb_max));
        if (d.x == -1.f && d.y == -1.f && d.z == -1.f && d.w == -1.f) cent = -1.f;
        float* o = pred_out + (size_t)i * 5;
        o[0] = b0; o[1] = b1; o[2] = b2; o[3] = b3; o[4] = cent;
    } else if (blk < 64 + RANKB) {
        // ---- rank (wave-per-box, 4 boxes/wave) + raw sorted scatter ----
        for (int i = t; i < NB; i += 256) sh[i] = scores[i];
        __syncthreads();
        int wave = t >> 6, lane = t & 63;
        int base = (blk - 64) * 16 + wave * 4;     // 4 consecutive boxes
        float my0 = sh[base + 0], my1 = sh[base + 1];
        float my2 = sh[base + 2], my3 = sh[base + 3];
        int c0 = 0, c1 = 0, c2 = 0, c3 = 0;
#pragma unroll 8
        for (int k = 0; k < 64; ++k) {
            int j = lane + k * 64;                 // 2-way LDS bank alias: free
            float sj = sh[j];
            c0 += (sj > my0) || (sj == my0 && j < base + 0);
            c1 += (sj > my1) || (sj == my1 && j < base + 1);
            c2 += (sj > my2) || (sj == my2 && j < base + 2);
            c3 += (sj > my3) || (sj == my3 && j < base + 3);
        }
        for (int o = 32; o > 0; o >>= 1) {
            c0 += __shfl_down(c0, o); c1 += __shfl_down(c1, o);
            c2 += __shfl_down(c2, o); c3 += __shfl_down(c3, o);
        }
        if (lane == 0) {
            int rk[4] = { c0, c1, c2, c3 };
#pragma unroll
            for (int k = 0; k < 4; ++k) {
                int i = base + k, rank = rk[k];
                sidx[rank] = i;
                ((float4*)sboxes)[rank] = ((const float4*)boxes)[i];
                scls[rank] = cls[i];
            }
        }
    } else {
        // ---- maxc (once) + zero bucket counts + donec + master ----
        if (t < 2 * NBLK + 1) counts[t] = 0;
        float m = -3.0e38f;
        for (int i = t; i < NB * 4; i += 256) m = fmaxf(m, boxes[i]);
        for (int o = 32; o > 0; o >>= 1) m = fmaxf(m, __shfl_down(m, o));
        if ((t & 63) == 0) red[t >> 6] = m;
        __syncthreads();
        if (t == 0) *maxc = fmaxf(fmaxf(red[0], red[1]), fmaxf(red[2], red[3]));
    }
}

// -------- edge extraction (coalesced, offsets applied here) + tail scan ------
// Entry (16 B): qword0 = local_row | (word_col<<8), qword1 = suppression word.
// Entries written with device-scope 64-bit atomics (coherent point, no release
// fence). 2-level done tree (round-9/10 lessons). Scan tail: pass1/pass2 use
// per-lane-owned entries + LDS ds_or_b64 — zero entry readlanes (round-10
// lesson: 60 serialized readlanes/block was ~30 us of the 48.9).
__global__ void __launch_bounds__(64) edge_kernel(
        const float* __restrict__ sboxes, const int* __restrict__ scls,
        const int* __restrict__ sidx, const float* __restrict__ maxc,
        int* __restrict__ counts /* [64 buckets][64 donec][1 master] */,
        uint4* __restrict__ entries, float* __restrict__ keep_out) {
    // decode upper-triangle tile (r <= c) from linear block id (uniform scalar)
    int idx = blockIdx.x, r = 0;
    while (idx >= NBLK - r) { idx -= NBLK - r; ++r; }
    int c = r + idx;

    __shared__ float4 cb[64];
    __shared__ float ca[64];
    __shared__ u64 lw[64];
    __shared__ int islast;
    int t = threadIdx.x;                // 64 threads = one wave
    float mc1 = maxc[0] + 1.0f;

    // row-tile box: sorted raw + class offset (bit-exact vs reference)
    float4 rb = ((const float4*)sboxes)[r * 64 + t];
    float offr = (float)scls[r * 64 + t] * mc1;
    rb.x += offr; rb.y += offr; rb.z += offr; rb.w += offr;
    float ra = (rb.z - rb.x) * (rb.w - rb.y);

    if (c == r) {
        cb[t] = rb; ca[t] = ra;
    } else {
        float4 b = ((const float4*)sboxes)[c * 64 + t];
        float offc = (float)scls[c * 64 + t] * mc1;
        b.x += offc; b.y += offc; b.z += offc; b.w += offc;
        cb[t] = b; ca[t] = (b.z - b.x) * (b.w - b.y);
    }
    __syncthreads();

    u64 w = 0;
#pragma unroll 8
    for (int j = 0; j < 64; ++j) {
        float4 b = cb[j];
        float xi = fminf(rb.z, b.z) - fmaxf(rb.x, b.x);
        float yi = fminf(rb.w, b.w) - fmaxf(rb.y, b.y);
        float inter = fmaxf(xi, 0.f) * fmaxf(yi, 0.f);
        float iou = inter / (ra + ca[j] - inter);
        w |= (u64)(iou > IOU_THR) << j;
    }
    if (c == r) w &= ~(1ull << t);      // drop self-overlap bit
    if (w) {
        int slot = atomicAdd(&counts[r], 1);
        if (slot < ECAP) {
            u64* e = (u64*)&entries[r * ECAP + slot];
            atomicExch(e,     (u64)(unsigned)(t | (c << 8)));  // meta qword
            atomicExch(e + 1, w);                              // word qword
        }
    }

    // ---- 2-level done signaling (deadlock-free: all work first) ----
    asm volatile("s_waitcnt vmcnt(0)" ::: "memory");  // own atomics complete
    if (t == 0) {
        islast = 0;
        int old = atomicAdd(&counts[NBLK + r], 1);        // bucket r done count
        if (old == (NBLK - r) - 1) {                      // bucket complete
            int o2 = atomicAdd(&counts[2 * NBLK], 1);     // master
            islast = (o2 == NBLK - 1);
        }
    }
    __syncthreads();
    if (!islast) return;
    __threadfence();                    // acquire: invalidate stale L1/L2 once

    // ================= serial greedy scan (this one wave) =================
    const int lane = t;
    int cnt_l = counts[lane];           // lane b holds bucket b's entry count
    u64 accv = 0;                       // lane w = removed-word w
    u64 keptall = 0;                    // lane b = keptm of block b
    u64 self = 1ull << lane;

    uint4 cur = entries[lane];          // depth-2 prefetch
    uint4 n1  = entries[ECAP + lane];
    for (int b = 0; b < NBLK; ++b) {
        uint4 n2;
        if (b < NBLK - 2) n2 = entries[(u64)(b + 2) * ECAP + lane];

        int cnt = __builtin_amdgcn_readlane(cnt_l, b);
        if (cnt > ECAP) cnt = ECAP;
        int cfast = cnt < 64 ? cnt : 64;

        // lane e owns entry e of this bucket (no readlanes on entries)
        bool mine = lane < cfast;
        int  el = (int)(cur.x & 255u);          // local row in bucket b
        int  ec = (int)((cur.x >> 8) & 255u);   // word column
        u64  ew = ((u64)cur.w << 32) | cur.z;   // suppression word

        // pass 1: build within-block column words via LDS OR
        lw[lane] = 0;
        __syncthreads();
        if (mine && ec == b) atomicOr(&lw[el & 63], ew);
        __syncthreads();
        u64 colw = lw[lane] | self;
        for (int e = 64; e < cnt; ++e) {        // overflow path (rare)
            uint4 x = entries[(u64)b * ECAP + e];
            int l = x.x & 255, cw = (x.x >> 8) & 255;
            if (cw == b && lane == l) colw |= ((u64)x.w << 32) | x.z;
        }

        // decision: optimistic ballot; serial greedy only over conflicts
        u64 rem = readlane64(accv, b);
        u64 avail = ~rem;
        u64 edges = colw & avail & ~self;
        u64 involved = __ballot(edges != 0ull) & avail;
        u64 keptm = avail & ~involved;
        u64 sub = involved;
        while (sub) {
            int i = (int)__builtin_ctzll(sub);  // highest score first
            keptm |= 1ull << i;
            u64 ci = readlane64(colw, i);
            sub &= ~(ci | (1ull << i));
        }
        if (lane == b) keptall = keptm;

        // pass 2: merge kept rows' words into removed accumulator via LDS OR
        lw[lane] = 0;
        __syncthreads();
        if (mine && ((keptm >> el) & 1ull)) atomicOr(&lw[ec & 63], ew);
        __syncthreads();
        accv |= lw[lane];
        for (int e = 64; e < cnt; ++e) {        // overflow path (rare)
            uint4 x = entries[(u64)b * ECAP + e];
            int l = x.x & 255, cw = (x.x >> 8) & 255;
            if (((keptm >> l) & 1ull) && lane == cw) accv |= ((u64)x.w << 32) | x.z;
        }
        cur = n1; n1 = n2;
    }

    // epilogue: write keep mask via sorted-index scatter
#pragma unroll 8
    for (int bb = 0; bb < NBLK; ++bb) {
        u64 kw = readlane64(keptall, bb);
        int oidx = sidx[bb * 64 + lane];
        keep_out[oidx] = ((kw >> lane) & 1ull) ? 1.0f : 0.0f;
    }
}

extern "C" void kernel_launch(void* const* d_in, const int* in_sizes, int n_in,
                              void* d_out, int out_size, void* d_ws, size_t ws_size,
                              hipStream_t stream) {
    const float* boxes   = (const float*)d_in[0];   // (4096,4)
    const float* scores  = (const float*)d_in[1];   // (4096,)
    const int*   cls     = (const int*)d_in[2];     // (4096,)
    const float* loc     = (const float*)d_in[3];   // (16384,2)
    const float* deltas  = (const float*)d_in[4];   // (16384,4)
    const int*   stride  = (const int*)d_in[5];     // scalar

    float* out = (float*)d_out;
    float* keep_out = out;          // 4096 floats (bool as 0/1)
    float* pred_out = out + NB;     // 16384*5 floats

    // workspace layout (16B-aligned pieces), ~1.1 MiB total
    char* ws = (char*)d_ws;
    float* maxc    = (float*)ws;                     ws += 16;
    int*   sidx    = (int*)ws;                       ws += NB * sizeof(int);
    float* sboxes  = (float*)ws;                     ws += NB * 4 * sizeof(float);
    int*   scls    = (int*)ws;                       ws += NB * sizeof(int);
    int*   counts  = (int*)ws;                       ws += (2 * NBLK + 1) * sizeof(int) + 12;
    uint4* entries = (uint4*)ws;                     // NBLK * ECAP * 16 B = 1 MiB

    fused_front<<<64 + RANKB + 1, 256, 0, stream>>>(boxes, scores, cls, loc, deltas,
                                                    stride, pred_out, sidx, sboxes,
                                                    scls, maxc, counts);
    edge_kernel<<<NTRI, 64, 0, stream>>>(sboxes, scls, sidx, maxc, counts, entries,
                                         keep_out);
}